// Round 9
// baseline (822.282 us; speedup 1.0000x reference)
//
#include <hip/hip_runtime.h>

typedef unsigned short u16;
typedef short short8 __attribute__((ext_vector_type(8)));
typedef float floatx4 __attribute__((ext_vector_type(4)));

#define H_ 4096
#define NH_ 32
#define NKV_ 8
#define HD_ 128
#define SEQ_ 2048
#define BATCH_ 2
#define ROWS_ (BATCH_*SEQ_)          // 4096
#define KVW_ (NKV_*HD_)              // 1024
#define NQKV_ (H_ + 2*KVW_)          // 6144 fused projection width
#define VSTRIDE_ NQKV_               // V rows live in fused QKV buffer
#define SCALE_ 0.08838834764831845f  // 128^-0.5
#define TSCALE_ (SCALE_*1.442695040888963f)   // fold log2e -> use exp2

__device__ __forceinline__ u16 f2bf(float f) {
  union { float f; unsigned u; } x; x.f = f;
  unsigned r = x.u + 0x7fffu + ((x.u >> 16) & 1u);   // RNE
  return (u16)(r >> 16);
}
__device__ __forceinline__ float bf2f(u16 h) {
  union { unsigned u; float f; } x; x.u = ((unsigned)h) << 16;
  return x.f;
}
// packed f32x2 -> bf16x2 (RNE), single instruction
__device__ __forceinline__ unsigned cvt_pk_bf16(float lo, float hi) {
  unsigned r;
  asm("v_cvt_pk_bf16_f32 %0, %1, %2" : "=v"(r) : "v"(lo), "v"(hi));
  return r;
}

// ---------------- fp32 -> bf16 convert ----------------
__global__ __launch_bounds__(256) void cvt_f32_bf16(const float* __restrict__ src,
                                                    u16* __restrict__ dst, int n4) {
  int i = blockIdx.x * 256 + threadIdx.x;
  if (i >= n4) return;
  float4 v = ((const float4*)src)[i];
  ushort4 o;
  o.x = f2bf(v.x); o.y = f2bf(v.y); o.z = f2bf(v.z); o.w = f2bf(v.w);
  ((ushort4*)dst)[i] = o;
}

// ---------------- concat bias: [0 x 4096 | bk | bv] ----------------
__global__ __launch_bounds__(256) void bias_concat(const float* __restrict__ bk,
                                                   const float* __restrict__ bv,
                                                   float* __restrict__ dst) {
  int i = blockIdx.x * 256 + threadIdx.x;
  if (i >= NQKV_) return;
  float v = 0.f;
  if (i >= H_ + KVW_)      v = bv[i - (H_ + KVW_)];
  else if (i >= H_)        v = bk[i - H_];
  dst[i] = v;
}

// ---------------- 256x256 8-phase GEMM (m201 schedule) ----------------
// Used for Wo projection (grid 256 = exactly 1 full round).
template<int BF16_OUT, int HAS_BIAS>
__global__ __launch_bounds__(512, 2) void gemm_nt_8p(const u16* __restrict__ A, const u16* __restrict__ B,
                                                     const float* __restrict__ bias, void* __restrict__ Cout,
                                                     int M, int N, int K)
{
  __shared__ __align__(16) u16 lds[65536];   // 128 KB: A bytes [0,64K), B bytes [64K,128K)
  char* ldsB = (char*)lds;
  const int tid  = threadIdx.x;
  const int lane = tid & 63;
  const int wave = tid >> 6;        // 0..7
  const int ln   = lane & 15;
  const int quad = lane >> 4;
  const int wm   = wave >> 2;       // 0..1 (M half)
  const int wn   = wave & 3;        // 0..3 (N quarter)

  // XCD-aware block swizzle (nwg % 8 == 0 for all shapes used here)
  const int NB  = N >> 8;
  const int nwg = gridDim.x;
  const int cpx = nwg >> 3;
  const int l   = (blockIdx.x & 7) * cpx + (blockIdx.x >> 3);
  const int m0  = (l / NB) * 256;
  const int n0  = (l % NB) * 256;

  // staging source pointers: half h: 0=A_k0 1=B_k0 2=A_k1 3=B_k1; j = glds issue (0,1)
  const u16* srcp[4][2];
  {
    int ob0 = wave*2048 + lane*16;
#pragma unroll
    for (int h = 0; h < 4; ++h) {
#pragma unroll
      for (int j = 0; j < 2; ++j) {
        int ob  = ob0 + j*1024;
        int row = ob >> 6;                             // 64 B per row (one kst half)
        int sl  = ((ob >> 4) & 3) ^ ((row >> 1) & 3);  // inverse swizzle on source
        int kst = h >> 1;
        if ((h & 1) == 0) srcp[h][j] = A + (size_t)(m0 + row)*K + kst*32 + sl*8;
        else              srcp[h][j] = B + (size_t)(n0 + row)*K + kst*32 + sl*8;
      }
    }
  }

#define STAGE(h_, p_, kt_)                                                          \
  {                                                                                 \
    __builtin_amdgcn_global_load_lds(                                               \
      (const __attribute__((address_space(1))) void*)(srcp[h_][0] + (kt_)*64),      \
      (__attribute__((address_space(3))) void*)(ldsB + (((h_)&1)*65536 + (p_)*32768 \
          + ((h_)>>1)*16384 + wave*2048)), 16, 0, 0);                               \
    __builtin_amdgcn_global_load_lds(                                               \
      (const __attribute__((address_space(1))) void*)(srcp[h_][1] + (kt_)*64),      \
      (__attribute__((address_space(3))) void*)(ldsB + (((h_)&1)*65536 + (p_)*32768 \
          + ((h_)>>1)*16384 + wave*2048 + 1024)), 16, 0, 0);                        \
  }

  // ds_read lane offsets (swizzled slot; lane-constant since (row>>1)&3 == (ln>>1)&3)
  const int slq16 = (quad ^ ((ln >> 1) & 3)) * 16;
  const int aoffL = (wm*128 + ln)*64 + slq16;
  const int boffL = (wn*64  + ln)*64 + slq16;

  floatx4 zf = {0.f, 0.f, 0.f, 0.f};
  floatx4 acc[8][4];
#pragma unroll
  for (int i = 0; i < 8; ++i)
#pragma unroll
    for (int j = 0; j < 4; ++j) acc[i][j] = zf;

  // prologue: stage tile 0 (queue: h0,h1,h2,h3 = 8 loads); confirm h0,h1 (kst0)
  STAGE(0, 0, 0) STAGE(1, 0, 0) STAGE(2, 0, 0) STAGE(3, 0, 0)
  asm volatile("s_waitcnt vmcnt(4)");
  __builtin_amdgcn_s_barrier();

  const int NT = K >> 6;
  for (int t = 0; t < NT; ++t) {
    const int p  = t & 1;
    const int np = p ^ 1;
    const char* ab = ldsB + p*32768;            // A, kst0
    const char* bb = ldsB + 65536 + p*32768;    // B, kst0
    short8 af[4], bq[4];

    // ---- PH0: kst0, m-frags 0..3 ----
#pragma unroll
    for (int j = 0; j < 4; ++j) bq[j] = *(const short8*)(bb + boffL + j*1024);
#pragma unroll
    for (int i = 0; i < 4; ++i) af[i] = *(const short8*)(ab + aoffL + i*1024);
    if (t + 1 < NT) STAGE(0, np, t+1)
    __builtin_amdgcn_s_barrier();
    asm volatile("s_waitcnt lgkmcnt(0)");
    __builtin_amdgcn_sched_barrier(0);
    __builtin_amdgcn_s_setprio(1);
#pragma unroll
    for (int i = 0; i < 4; ++i)
#pragma unroll
      for (int j = 0; j < 4; ++j)
        acc[i][j] = __builtin_amdgcn_mfma_f32_16x16x32_bf16(af[i], bq[j], acc[i][j], 0, 0, 0);
    __builtin_amdgcn_s_setprio(0);
    __builtin_amdgcn_s_barrier();

    // ---- PH1: kst0, m-frags 4..7 (bq reused); end: confirm kst1 halves of t ----
#pragma unroll
    for (int i = 0; i < 4; ++i) af[i] = *(const short8*)(ab + aoffL + (4+i)*1024);
    if (t + 1 < NT) STAGE(1, np, t+1)
    __builtin_amdgcn_s_barrier();
    asm volatile("s_waitcnt lgkmcnt(0)");
    __builtin_amdgcn_sched_barrier(0);
    __builtin_amdgcn_s_setprio(1);
#pragma unroll
    for (int i = 0; i < 4; ++i)
#pragma unroll
      for (int j = 0; j < 4; ++j)
        acc[4+i][j] = __builtin_amdgcn_mfma_f32_16x16x32_bf16(af[i], bq[j], acc[4+i][j], 0, 0, 0);
    __builtin_amdgcn_s_setprio(0);
    if (t + 1 < NT) { asm volatile("s_waitcnt vmcnt(4)"); }   // h2,h3(t) landed
    else            { asm volatile("s_waitcnt vmcnt(0)"); }   // last tile: drain
    __builtin_amdgcn_s_barrier();

    // ---- PH2: kst1, m-frags 0..3 ----
#pragma unroll
    for (int j = 0; j < 4; ++j) bq[j] = *(const short8*)(bb + 16384 + boffL + j*1024);
#pragma unroll
    for (int i = 0; i < 4; ++i) af[i] = *(const short8*)(ab + 16384 + aoffL + i*1024);
    if (t + 1 < NT) STAGE(2, np, t+1)
    __builtin_amdgcn_s_barrier();
    asm volatile("s_waitcnt lgkmcnt(0)");
    __builtin_amdgcn_sched_barrier(0);
    __builtin_amdgcn_s_setprio(1);
#pragma unroll
    for (int i = 0; i < 4; ++i)
#pragma unroll
      for (int j = 0; j < 4; ++j)
        acc[i][j] = __builtin_amdgcn_mfma_f32_16x16x32_bf16(af[i], bq[j], acc[i][j], 0, 0, 0);
    __builtin_amdgcn_s_setprio(0);
    __builtin_amdgcn_s_barrier();

    // ---- PH3: kst1, m-frags 4..7; end: confirm kst0 halves of t+1 ----
#pragma unroll
    for (int i = 0; i < 4; ++i) af[i] = *(const short8*)(ab + 16384 + aoffL + (4+i)*1024);
    if (t + 1 < NT) STAGE(3, np, t+1)
    __builtin_amdgcn_s_barrier();
    asm volatile("s_waitcnt lgkmcnt(0)");
    __builtin_amdgcn_sched_barrier(0);
    __builtin_amdgcn_s_setprio(1);
#pragma unroll
    for (int i = 0; i < 4; ++i)
#pragma unroll
      for (int j = 0; j < 4; ++j)
        acc[4+i][j] = __builtin_amdgcn_mfma_f32_16x16x32_bf16(af[i], bq[j], acc[4+i][j], 0, 0, 0);
    __builtin_amdgcn_s_setprio(0);
    if (t + 1 < NT) { asm volatile("s_waitcnt vmcnt(4)"); }   // h0,h1(t+1) landed
    __builtin_amdgcn_s_barrier();
  }
#undef STAGE

  // ---- epilogue ----
#pragma unroll
  for (int i = 0; i < 8; ++i) {
#pragma unroll
    for (int j = 0; j < 4; ++j) {
      int row = m0 + wm*128 + i*16 + quad*4;
      int col = n0 + wn*64  + j*16 + ln;
      float bv_ = HAS_BIAS ? bias[col] : 0.f;
#pragma unroll
      for (int r = 0; r < 4; ++r) {
        float v = acc[i][j][r] + bv_;
        if (BF16_OUT) ((u16*)Cout)[(size_t)(row+r)*N + col] = f2bf(v);
        else          ((float*)Cout)[(size_t)(row+r)*N + col] = v;
      }
    }
  }
}

// ---------------- 128x256 2-phase GEMM (m201 schedule, half-M tile) ----------------
// Used for QKV projection: grid = (4096/128)*(6144/256) = 32*24 = 768 = EXACTLY 3 full
// rounds of 256 CUs (the 256^2 tile gave 384 blocks = 1.5 rounds -> 25% tail waste).
// 512 threads (8 waves, 2M x 4N; each wave 64x64), BK=64, LDS 96 KB dbuf.
// Per K-tile: 6 staged loads (A_k:1, B_k:2 per kst); per phase: 8 ds_read_b128,
// STAGE one kst of t+1 (3 loads), barrier, lgkmcnt(0), 16 MFMA; phase-end vmcnt(3)
// confirms the kst staged 2 phases earlier. Never vmcnt(0) mid-loop.
// Slot swizzle phys = quad ^ ((row>>1)&3) on glds source AND ds_read (involution).
template<int BF16_OUT, int HAS_BIAS>
__global__ __launch_bounds__(512, 2) void gemm_nt_8p_h(const u16* __restrict__ A, const u16* __restrict__ B,
                                                       const float* __restrict__ bias, void* __restrict__ Cout,
                                                       int M, int N, int K)
{
  __shared__ __align__(16) u16 lds[49152];   // 96 KB: A [0,32K) {p:16K, kst:8K}, B [32K,96K) {p:32K, kst:16K}
  char* ldsB = (char*)lds;
  const int tid  = threadIdx.x;
  const int lane = tid & 63;
  const int wave = tid >> 6;        // 0..7
  const int ln   = lane & 15;
  const int quad = lane >> 4;
  const int wm   = wave >> 2;       // 0..1 (M half: 64 rows)
  const int wn   = wave & 3;        // 0..3 (N quarter: 64 cols)

  // XCD-aware block swizzle (768 % 8 == 0)
  const int NB  = N >> 8;           // n-tiles of 256
  const int nwg = gridDim.x;
  const int cpx = nwg >> 3;
  const int l   = (blockIdx.x & 7) * cpx + (blockIdx.x >> 3);
  const int m0  = (l / NB) * 128;
  const int n0  = (l % NB) * 256;

  // staging sources: A half = 8 KB (1 glds/wave), B half = 16 KB (2 glds/wave)
  const u16* srcA[2];
  const u16* srcB[2][2];
  {
    int ob  = wave*1024 + lane*16;
    int row = ob >> 6;
    int sl  = ((ob >> 4) & 3) ^ ((row >> 1) & 3);
#pragma unroll
    for (int kst = 0; kst < 2; ++kst)
      srcA[kst] = A + (size_t)(m0 + row)*K + kst*32 + sl*8;
  }
#pragma unroll
  for (int j = 0; j < 2; ++j) {
    int ob  = wave*2048 + j*1024 + lane*16;
    int row = ob >> 6;
    int sl  = ((ob >> 4) & 3) ^ ((row >> 1) & 3);
#pragma unroll
    for (int kst = 0; kst < 2; ++kst)
      srcB[kst][j] = B + (size_t)(n0 + row)*K + kst*32 + sl*8;
  }

#define STAGEH(kst_, p_, kt_)                                                        \
  {                                                                                  \
    __builtin_amdgcn_global_load_lds(                                                \
      (const __attribute__((address_space(1))) void*)(srcA[kst_] + (kt_)*64),        \
      (__attribute__((address_space(3))) void*)(ldsB + ((p_)*16384 + (kst_)*8192     \
          + wave*1024)), 16, 0, 0);                                                  \
    __builtin_amdgcn_global_load_lds(                                                \
      (const __attribute__((address_space(1))) void*)(srcB[kst_][0] + (kt_)*64),     \
      (__attribute__((address_space(3))) void*)(ldsB + (32768 + (p_)*32768           \
          + (kst_)*16384 + wave*2048)), 16, 0, 0);                                   \
    __builtin_amdgcn_global_load_lds(                                                \
      (const __attribute__((address_space(1))) void*)(srcB[kst_][1] + (kt_)*64),     \
      (__attribute__((address_space(3))) void*)(ldsB + (32768 + (p_)*32768           \
          + (kst_)*16384 + wave*2048 + 1024)), 16, 0, 0);                            \
  }

  // ds_read lane offsets
  const int slq16 = (quad ^ ((ln >> 1) & 3)) * 16;
  const int aoffL = (wm*64 + ln)*64 + slq16;
  const int boffL = (wn*64 + ln)*64 + slq16;

  floatx4 zf = {0.f, 0.f, 0.f, 0.f};
  floatx4 acc[4][4];
#pragma unroll
  for (int i = 0; i < 4; ++i)
#pragma unroll
    for (int j = 0; j < 4; ++j) acc[i][j] = zf;

  // prologue: stage tile 0 (6 loads: kst0 = 3, kst1 = 3); confirm kst0
  STAGEH(0, 0, 0) STAGEH(1, 0, 0)
  asm volatile("s_waitcnt vmcnt(3)");
  __builtin_amdgcn_s_barrier();

  const int NT = K >> 6;
  for (int t = 0; t < NT; ++t) {
    const int p  = t & 1;
    const int np = p ^ 1;
    const char* ab = ldsB + p*16384;
    const char* bb = ldsB + 32768 + p*32768;
    short8 af[4], bq[4];

    // ---- PH0: kst0 ----
#pragma unroll
    for (int j = 0; j < 4; ++j) bq[j] = *(const short8*)(bb + boffL + j*1024);
#pragma unroll
    for (int i = 0; i < 4; ++i) af[i] = *(const short8*)(ab + aoffL + i*1024);
    if (t + 1 < NT) STAGEH(0, np, t+1)
    __builtin_amdgcn_s_barrier();
    asm volatile("s_waitcnt lgkmcnt(0)");
    __builtin_amdgcn_sched_barrier(0);
    __builtin_amdgcn_s_setprio(1);
#pragma unroll
    for (int i = 0; i < 4; ++i)
#pragma unroll
      for (int j = 0; j < 4; ++j)
        acc[i][j] = __builtin_amdgcn_mfma_f32_16x16x32_bf16(af[i], bq[j], acc[i][j], 0, 0, 0);
    __builtin_amdgcn_s_setprio(0);
    if (t + 1 < NT) { asm volatile("s_waitcnt vmcnt(3)"); }   // kst1(t) landed
    else            { asm volatile("s_waitcnt vmcnt(0)"); }   // last tile: drain
    __builtin_amdgcn_s_barrier();

    // ---- PH1: kst1; end: confirm kst0 of t+1 ----
#pragma unroll
    for (int j = 0; j < 4; ++j) bq[j] = *(const short8*)(bb + 16384 + boffL + j*1024);
#pragma unroll
    for (int i = 0; i < 4; ++i) af[i] = *(const short8*)(ab + 8192 + aoffL + i*1024);
    if (t + 1 < NT) STAGEH(1, np, t+1)
    __builtin_amdgcn_s_barrier();
    asm volatile("s_waitcnt lgkmcnt(0)");
    __builtin_amdgcn_sched_barrier(0);
    __builtin_amdgcn_s_setprio(1);
#pragma unroll
    for (int i = 0; i < 4; ++i)
#pragma unroll
      for (int j = 0; j < 4; ++j)
        acc[i][j] = __builtin_amdgcn_mfma_f32_16x16x32_bf16(af[i], bq[j], acc[i][j], 0, 0, 0);
    __builtin_amdgcn_s_setprio(0);
    if (t + 1 < NT) { asm volatile("s_waitcnt vmcnt(3)"); }   // kst0(t+1) landed
    __builtin_amdgcn_s_barrier();
  }
#undef STAGEH

  // ---- epilogue ----
#pragma unroll
  for (int i = 0; i < 4; ++i) {
#pragma unroll
    for (int j = 0; j < 4; ++j) {
      int row = m0 + wm*64 + i*16 + quad*4;
      int col = n0 + wn*64 + j*16 + ln;
      float bv_ = HAS_BIAS ? bias[col] : 0.f;
#pragma unroll
      for (int r = 0; r < 4; ++r) {
        float v = acc[i][j][r] + bv_;
        if (BF16_OUT) ((u16*)Cout)[(size_t)(row+r)*N + col] = f2bf(v);
        else          ((float*)Cout)[(size_t)(row+r)*N + col] = v;
      }
    }
  }
}

// ---------------- RoPE (strided in/out: reads fused QKV buffer) ----------------
__global__ __launch_bounds__(256) void rope_kernel(const u16* __restrict__ X, u16* __restrict__ Y,
                                                   const float* __restrict__ cosb, const float* __restrict__ sinb,
                                                   int nheads, int total, int istride, int ostride)
{
  int idx = blockIdx.x * 256 + threadIdx.x;
  if (idx >= total) return;
  int d = idx & 63;
  int t = idx >> 6;
  int hh = t % nheads;
  int row = t / nheads;
  int s = row & (SEQ_ - 1);
  size_t bi = (size_t)row * istride + hh * HD_;
  size_t bo = (size_t)row * ostride + hh * HD_;
  float x1 = bf2f(X[bi + 2*d]);
  float x2 = bf2f(X[bi + 2*d + 1]);
  float c  = cosb[s*64 + d];
  float sn = sinb[s*64 + d];
  Y[bo + d]      = f2bf(x1*c - x2*sn);
  Y[bo + 64 + d] = f2bf(x1*sn + x2*c);
}

// ---------------- Flash attention (GQA, no mask) ----------------
// 8-wave, launch_bounds(512,2); 512 blocks = 2 resident/CU, 16 waves/CU.
// SWAPPED QK^T, kappa P-layout, defer-max, async K/V staging (see R6 notes).
#define KS_TILE (64*128)

__global__ __launch_bounds__(512, 2) void attn_fwd(const u16* __restrict__ Q, const u16* __restrict__ K,
                                                   const u16* __restrict__ V, u16* __restrict__ O)
{
  __shared__ __align__(16) u16 Ks[2*KS_TILE];  // double-buffered [key][dgp swizzled], 32 KB
  __shared__ __align__(16) u16 Vt[128*72];     // [d][kappa], stride 72, 18 KB
  const int tid  = threadIdx.x;
  const int lane = tid & 63;
  const int wave = tid >> 6;      // 0..7
  const int ln   = lane & 15;
  const int quad = lane >> 4;
  // bijective XCD swizzle: 512 blocks, 8 XCDs, 64 blocks/XCD; same-XCD blocks share bh range
  const int lin = (blockIdx.x & 7) * 64 + (blockIdx.x >> 3);
  const int bh  = lin >> 3;       // 0..63
  const int b   = bh >> 5;
  const int h   = bh & 31;
  const int kvh = h >> 2;
  const int q0  = (lin & 7) * 256;

  // Q fragments: B-layout for swapped mfma (n = ln = q-row, k = kst*32 + quad*8 + j)
  short8 qf[2][4];
#pragma unroll
  for (int mt = 0; mt < 2; ++mt) {
    const u16* qbase = Q + (size_t)(b*SEQ_ + q0 + wave*32 + mt*16 + ln) * H_ + h * HD_;
#pragma unroll
    for (int kst = 0; kst < 4; ++kst)
      qf[mt][kst] = *(const short8*)(qbase + kst*32 + quad*8);
  }

  // ones B-frag: B[k][n] = (n==0) ? 1 : 0  -> lanes with ln==0 hold bf16 1.0
  short8 bones;
  {
    short v1 = (ln == 0) ? (short)0x3F80 : (short)0;
#pragma unroll
    for (int j = 0; j < 8; ++j) bones[j] = v1;
  }

  // precomputed K staging addresses: 8 waves x 2 glds x 1 KB = 16 KB/tile
  int kou[2];
  const u16* ks0[2];
#pragma unroll
  for (int i = 0; i < 2; ++i) {
    int ou = wave*2048 + i*1024;          // wave-uniform LDS byte offset
    int ob = ou + lane*16;                // this lane's dest byte
    int key = ob >> 8;                    // 256 B per key row
    int dgp = (ob >> 4) & 15;
    int dgl = dgp ^ (key & 15);
    kou[i] = ou;
    ks0[i] = K + (size_t)(b*SEQ_ + key)*KVW_ + kvh*HD_ + dgl*8;
  }
  // V staging: thread (j2, dg, g) loads keys (j2*2+jj)*16+g (jj=0,1), d-block dg
  const int g  = tid & 15;
  const int dg = (tid >> 4) & 15;
  const int j2 = tid >> 8;              // 0..1
  const u16* vs0 = V + (size_t)(b*SEQ_ + j2*32 + g)*VSTRIDE_ + kvh*HD_ + dg*8;
  const int k0v = ((g >> 1) & 1)*32 + (g >> 2)*8 + (g & 1)*4 + j2*2;  // kappa base

  floatx4 zf = {0.f, 0.f, 0.f, 0.f};
  floatx4 o[2][8];
  floatx4 ol[2];
#pragma unroll
  for (int mt = 0; mt < 2; ++mt) {
    ol[mt] = zf;
#pragma unroll
    for (int jt = 0; jt < 8; ++jt) o[mt][jt] = zf;
  }
  float mrow[2] = {-1e30f, -1e30f};   // running max for q = ln (t-domain)

  // ---- prologue: stage tile 0 ----
  int4 vreg[2];
#pragma unroll
  for (int i = 0; i < 2; ++i)
    __builtin_amdgcn_global_load_lds((const __attribute__((address_space(1))) void*)ks0[i],
        (__attribute__((address_space(3))) void*)((char*)Ks + kou[i]), 16, 0, 0);
#pragma unroll
  for (int jj = 0; jj < 2; ++jj)
    vreg[jj] = *(const int4*)(vs0 + (size_t)(jj*16)*VSTRIDE_);
  {
    union { int4 v; u16 u[8]; } w[2];
    w[0].v = vreg[0]; w[1].v = vreg[1];
#pragma unroll
    for (int dd = 0; dd < 8; ++dd) {
      ushort2 t2; t2.x = w[0].u[dd]; t2.y = w[1].u[dd];
      *(ushort2*)&Vt[(dg*8 + dd)*72 + k0v] = t2;
    }
  }
  __syncthreads();

  const int NT = SEQ_ / 64;
  for (int t = 0; t < NT; ++t) {
    // ---- issue next tile's loads early (latency hides under compute) ----
    if (t + 1 < NT) {
      size_t roff = (size_t)(t+1) * 64 * KVW_;
      char* kb = (char*)Ks + ((t+1)&1) * (KS_TILE*2);
#pragma unroll
      for (int i = 0; i < 2; ++i)
        __builtin_amdgcn_global_load_lds((const __attribute__((address_space(1))) void*)(ks0[i] + roff),
            (__attribute__((address_space(3))) void*)(kb + kou[i]), 16, 0, 0);
      size_t voff = (size_t)(t+1) * 64 * VSTRIDE_;
#pragma unroll
      for (int jj = 0; jj < 2; ++jj)
        vreg[jj] = *(const int4*)(vs0 + voff + (size_t)(jj*16)*VSTRIDE_);
    }
    const u16* Kc = Ks + (t&1)*KS_TILE;

    // ---- S^T = K Q^T (swapped): lane holds q=ln, keys nt*16+quad*4+r ----
    floatx4 s[2][4];
#pragma unroll
    for (int nt = 0; nt < 4; ++nt) { s[0][nt] = zf; s[1][nt] = zf; }
    __builtin_amdgcn_s_setprio(1);
#pragma unroll
    for (int kst = 0; kst < 4; ++kst) {
      int dgp = (kst*4 + quad) ^ ln;
#pragma unroll
      for (int nt = 0; nt < 4; ++nt) {
        short8 kf = *(const short8*)&Kc[(nt*16 + ln)*128 + dgp*8];
        s[0][nt] = __builtin_amdgcn_mfma_f32_16x16x32_bf16(kf, qf[0][kst], s[0][nt], 0, 0, 0);
        s[1][nt] = __builtin_amdgcn_mfma_f32_16x16x32_bf16(kf, qf[1][kst], s[1][nt], 0, 0, 0);
      }
    }
    __builtin_amdgcn_s_setprio(0);

    // ---- online softmax: lane-local 16-max + cross-quad reduce ----
    float rmv[2];
    bool ok = true;
#pragma unroll
    for (int mt = 0; mt < 2; ++mt) {
      float m0_ = fmaxf(fmaxf(s[mt][0][0], s[mt][0][1]), fmaxf(s[mt][0][2], s[mt][0][3]));
      float m1_ = fmaxf(fmaxf(s[mt][1][0], s[mt][1][1]), fmaxf(s[mt][1][2], s[mt][1][3]));
      float m2_ = fmaxf(fmaxf(s[mt][2][0], s[mt][2][1]), fmaxf(s[mt][2][2], s[mt][2][3]));
      float m3_ = fmaxf(fmaxf(s[mt][3][0], s[mt][3][1]), fmaxf(s[mt][3][2], s[mt][3][3]));
      float rm = fmaxf(fmaxf(m0_, m1_), fmaxf(m2_, m3_)) * TSCALE_;
      rm = fmaxf(rm, __shfl_xor(rm, 16));
      rm = fmaxf(rm, __shfl_xor(rm, 32));
      rmv[mt] = rm;
      ok = ok && (rm - mrow[mt] <= 8.0f);
    }
    // defer-max: rescale only when some row's max grew by > 8 (P bounded by 2^8)
    if (!__all(ok)) {
#pragma unroll
      for (int mt = 0; mt < 2; ++mt) {
        float mn = fmaxf(mrow[mt], rmv[mt]);
        float al = exp2f(mrow[mt] - mn);
        mrow[mt] = mn;
        float av[4];
#pragma unroll
        for (int r = 0; r < 4; ++r) av[r] = __shfl(al, (lane & 48) | (quad*4 + r));
#pragma unroll
        for (int r = 0; r < 4; ++r) {
          float a_ = av[r];
#pragma unroll
          for (int jt = 0; jt < 8; ++jt) o[mt][jt][r] *= a_;
          ol[mt][r] *= a_;
        }
      }
    }
    // ---- P = exp2(S*T - m), packed in-register directly into PV A-frags ----
    short8 pa[2][2];
#pragma unroll
    for (int mt = 0; mt < 2; ++mt) {
      float mn = mrow[mt];
      float p[4][4];
#pragma unroll
      for (int nt = 0; nt < 4; ++nt)
#pragma unroll
        for (int r = 0; r < 4; ++r)
          p[r][nt] = exp2f(fmaf(s[mt][nt][r], TSCALE_, -mn));
#pragma unroll
      for (int k2 = 0; k2 < 2; ++k2) {
        union { unsigned u[4]; short8 v; } pk;
        pk.u[0] = cvt_pk_bf16(p[2*k2][0],   p[2*k2][1]);
        pk.u[1] = cvt_pk_bf16(p[2*k2][2],   p[2*k2][3]);
        pk.u[2] = cvt_pk_bf16(p[2*k2+1][0], p[2*k2+1][1]);
        pk.u[3] = cvt_pk_bf16(p[2*k2+1][2], p[2*k2+1][3]);
        pa[mt][k2] = pk.v;
      }
    }

    // ---- O += P V (contraction over kappa; V-frags shared across m-tiles) ----
    __builtin_amdgcn_s_setprio(1);
#pragma unroll
    for (int k2 = 0; k2 < 2; ++k2) {
#pragma unroll
      for (int jt = 0; jt < 8; ++jt) {
        short8 vf = *(const short8*)&Vt[(jt*16 + ln)*72 + k2*32 + quad*8];
        o[0][jt] = __builtin_amdgcn_mfma_f32_16x16x32_bf16(pa[0][k2], vf, o[0][jt], 0, 0, 0);
        o[1][jt] = __builtin_amdgcn_mfma_f32_16x16x32_bf16(pa[1][k2], vf, o[1][jt], 0, 0, 0);
      }
      ol[0] = __builtin_amdgcn_mfma_f32_16x16x32_bf16(pa[0][k2], bones, ol[0], 0, 0, 0);
      ol[1] = __builtin_amdgcn_mfma_f32_16x16x32_bf16(pa[1][k2], bones, ol[1], 0, 0, 0);
    }
    __builtin_amdgcn_s_setprio(0);

    __syncthreads();                // all waves done reading Vt; vmcnt drained
    if (t + 1 < NT) {
      union { int4 v; u16 u[8]; } w[2];
      w[0].v = vreg[0]; w[1].v = vreg[1];
#pragma unroll
      for (int dd = 0; dd < 8; ++dd) {
        ushort2 t2; t2.x = w[0].u[dd]; t2.y = w[1].u[dd];
        *(ushort2*)&Vt[(dg*8 + dd)*72 + k0v] = t2;
      }
    }
    __syncthreads();                // next tile's Vt/Ks visible
  }

  // ---- epilogue: broadcast l from ln==0 lane of each quad, divide, store ----
#pragma unroll
  for (int mt = 0; mt < 2; ++mt) {
#pragma unroll
    for (int r = 0; r < 4; ++r) {
      float lv = __shfl(ol[mt][r], lane & 48);
      float inv = 1.f / lv;
      size_t row = (size_t)(b*SEQ_ + q0 + wave*32 + mt*16 + quad*4 + r);
      u16* dst = O + row * H_ + h * HD_ + ln;
#pragma unroll
      for (int jt = 0; jt < 8; ++jt)
        dst[jt*16] = f2bf(o[mt][jt][r] * inv);
    }
  }
}

// ---------------- host ----------------
extern "C" void kernel_launch(void* const* d_in, const int* in_sizes, int n_in,
                              void* d_out, int out_size, void* d_ws, size_t ws_size,
                              hipStream_t stream) {
  const float* hs   = (const float*)d_in[0];
  const float* cosb = (const float*)d_in[1];
  const float* sinb = (const float*)d_in[2];
  const float* Wq   = (const float*)d_in[3];
  const float* Wk   = (const float*)d_in[4];
  const float* bk   = (const float*)d_in[5];
  const float* Wv   = (const float*)d_in[6];
  const float* bv   = (const float*)d_in[7];
  const float* Wo   = (const float*)d_in[8];
  float* out = (float*)d_out;

  char* ws = (char*)d_ws;
  u16*   hs_bf   = (u16*)(ws +          0);  // 33,554,432 B (dead after QKV gemm)
  u16*   Wqkv_bf = (u16*)(ws +   33554432);  // 50,331,648  [6144][4096]
  u16*   Wo_bf   = (u16*)(ws +   83886080);  // 33,554,432
  u16*   QKV0    = (u16*)(ws +  117440512);  // 50,331,648  [4096][6144]
  u16*   Qr      = (u16*)(ws +  167772160);  // 33,554,432
  u16*   Kr      = (u16*)(ws +  201326592);  //  8,388,608
  float* biasqkv = (float*)(ws + 209715200); //     24,576
  u16*   Oa      = hs_bf;                    // alias: hs_bf dead before attn writes

  {
    int n;
    n = ROWS_*H_;  cvt_f32_bf16<<<(n/4 + 255)/256, 256, 0, stream>>>(hs, hs_bf, n/4);
    n = H_*H_;     cvt_f32_bf16<<<(n/4 + 255)/256, 256, 0, stream>>>(Wq, Wqkv_bf, n/4);
    n = KVW_*H_;   cvt_f32_bf16<<<(n/4 + 255)/256, 256, 0, stream>>>(Wk, Wqkv_bf + (size_t)H_*H_, n/4);
    n = KVW_*H_;   cvt_f32_bf16<<<(n/4 + 255)/256, 256, 0, stream>>>(Wv, Wqkv_bf + (size_t)(H_+KVW_)*H_, n/4);
    n = H_*H_;     cvt_f32_bf16<<<(n/4 + 255)/256, 256, 0, stream>>>(Wo, Wo_bf, n/4);
    bias_concat<<<(NQKV_ + 255)/256, 256, 0, stream>>>(bk, bv, biasqkv);
  }

  // fused Q|K|V projection: C[4096][6144], 32x24 = 768 blocks = exactly 3 full rounds
  gemm_nt_8p_h<1,1><<<dim3((ROWS_/128)*(NQKV_/256)), dim3(512), 0, stream>>>(hs_bf, Wqkv_bf, biasqkv, QKV0, ROWS_, NQKV_, H_);
  rope_kernel<<<(ROWS_*NH_*64)/256,  256, 0, stream>>>(QKV0,       Qr, cosb, sinb, NH_,  ROWS_*NH_*64,  NQKV_, H_);
  rope_kernel<<<(ROWS_*NKV_*64)/256, 256, 0, stream>>>(QKV0 + H_,  Kr, cosb, sinb, NKV_, ROWS_*NKV_*64, NQKV_, KVW_);
  // 512 blocks of 512 threads = exactly 2 blocks/CU, 16 waves/CU
  attn_fwd<<<dim3(512), dim3(512), 0, stream>>>(Qr, Kr, QKV0 + H_ + KVW_, Oa);
  // output projection: 16x16=256 blocks = exactly 1 full round (keep 256^2 tile)
  gemm_nt_8p<0,0><<<dim3((ROWS_/256)*(H_/256)), dim3(512), 0, stream>>>(Oa, Wo_bf, nullptr, out, ROWS_, H_, H_);
}

// Round 10
// 785.723 us; speedup vs baseline: 1.0465x; 1.0465x over previous
//
#include <hip/hip_runtime.h>

typedef unsigned short u16;
typedef short short8 __attribute__((ext_vector_type(8)));
typedef float floatx4 __attribute__((ext_vector_type(4)));

#define H_ 4096
#define NH_ 32
#define NKV_ 8
#define HD_ 128
#define SEQ_ 2048
#define BATCH_ 2
#define ROWS_ (BATCH_*SEQ_)          // 4096
#define KVW_ (NKV_*HD_)              // 1024
#define NQKV_ (H_ + 2*KVW_)          // 6144 fused projection width
#define VSTRIDE_ NQKV_               // V rows live in fused QKV buffer
#define SCALE_ 0.08838834764831845f  // 128^-0.5
#define TSCALE_ (SCALE_*1.442695040888963f)   // fold log2e -> use exp2

__device__ __forceinline__ u16 f2bf(float f) {
  union { float f; unsigned u; } x; x.f = f;
  unsigned r = x.u + 0x7fffu + ((x.u >> 16) & 1u);   // RNE
  return (u16)(r >> 16);
}
__device__ __forceinline__ float bf2f(u16 h) {
  union { unsigned u; float f; } x; x.u = ((unsigned)h) << 16;
  return x.f;
}
// packed f32x2 -> bf16x2 (RNE), single instruction
__device__ __forceinline__ unsigned cvt_pk_bf16(float lo, float hi) {
  unsigned r;
  asm("v_cvt_pk_bf16_f32 %0, %1, %2" : "=v"(r) : "v"(lo), "v"(hi));
  return r;
}

// ---------------- fused fp32 -> bf16 convert of all 5 tensors (1 launch) ----------------
// Regions (float4 units): hs 4,194,304 | Wq 4,194,304 | Wk 1,048,576 | Wv 1,048,576 | Wo 4,194,304
__global__ __launch_bounds__(256) void cvt_all(const float* __restrict__ hs, const float* __restrict__ Wq,
                                               const float* __restrict__ Wk, const float* __restrict__ Wv,
                                               const float* __restrict__ Wo,
                                               u16* __restrict__ hs_bf, u16* __restrict__ Wqkv_bf,
                                               u16* __restrict__ Wo_bf) {
  const int n_hs = ROWS_*H_/4;
  const int n_wq = H_*H_/4;
  const int n_wk = KVW_*H_/4;
  const long total = (long)n_hs + n_wq + 2*(long)n_wk + n_wq;
  for (long i = (long)blockIdx.x*256 + threadIdx.x; i < total; i += (long)gridDim.x*256) {
    const float* s; u16* d; long j = i;
    if (j < n_hs)                       { s = hs; d = hs_bf; }
    else if ((j -= n_hs) < n_wq)        { s = Wq; d = Wqkv_bf; }
    else if ((j -= n_wq) < n_wk)        { s = Wk; d = Wqkv_bf + (size_t)H_*H_; }
    else if ((j -= n_wk) < n_wk)        { s = Wv; d = Wqkv_bf + (size_t)(H_+KVW_)*H_; }
    else { j -= n_wk;                     s = Wo; d = Wo_bf; }
    float4 v = ((const float4*)s)[j];
    ushort4 o; o.x = f2bf(v.x); o.y = f2bf(v.y); o.z = f2bf(v.z); o.w = f2bf(v.w);
    ((ushort4*)d)[j] = o;
  }
}

// ---------------- concat bias: [0 x 4096 | bk | bv] ----------------
__global__ __launch_bounds__(256) void bias_concat(const float* __restrict__ bk,
                                                   const float* __restrict__ bv,
                                                   float* __restrict__ dst) {
  int i = blockIdx.x * 256 + threadIdx.x;
  if (i >= NQKV_) return;
  float v = 0.f;
  if (i >= H_ + KVW_)      v = bv[i - (H_ + KVW_)];
  else if (i >= H_)        v = bk[i - H_];
  dst[i] = v;
}

// ---------------- 256x256 8-phase GEMM (m201 schedule) ----------------
// Used ONLY for Wo projection: 16x16 tiles, 256 blocks = 1 exact round.
// 2D XCD rect swizzle: XCD grid 2x4 of 8m x 4n rects (A 16 MB + B 8 MB per XCD;
// A panels shared by 4 XCDs, B panels by 2) -> lower L2-fill than 1D walk.
template<int BF16_OUT, int HAS_BIAS>
__global__ __launch_bounds__(512, 2) void gemm_nt_8p(const u16* __restrict__ A, const u16* __restrict__ B,
                                                     const float* __restrict__ bias, void* __restrict__ Cout,
                                                     int M, int N, int K)
{
  __shared__ __align__(16) u16 lds[65536];   // 128 KB: A bytes [0,64K), B bytes [64K,128K)
  char* ldsB = (char*)lds;
  const int tid  = threadIdx.x;
  const int lane = tid & 63;
  const int wave = tid >> 6;        // 0..7
  const int ln   = lane & 15;
  const int quad = lane >> 4;
  const int wm   = wave >> 2;       // 0..1 (M half)
  const int wn   = wave & 3;        // 0..3 (N quarter)

  // 2D XCD rectangle swizzle (16x16 tiles, 256 blocks exactly)
  const int xcd = blockIdx.x & 7;
  const int k_  = blockIdx.x >> 3;                      // 0..31
  const int m0  = ((xcd >> 2) * 8 + (k_ & 7)) * 256;    // m-tile 0..15
  const int n0  = ((xcd & 3) * 4 + (k_ >> 3)) * 256;    // n-tile 0..15

  // staging source pointers: half h: 0=A_k0 1=B_k0 2=A_k1 3=B_k1; j = glds issue (0,1)
  const u16* srcp[4][2];
  {
    int ob0 = wave*2048 + lane*16;
#pragma unroll
    for (int h = 0; h < 4; ++h) {
#pragma unroll
      for (int j = 0; j < 2; ++j) {
        int ob  = ob0 + j*1024;
        int row = ob >> 6;                             // 64 B per row (one kst half)
        int sl  = ((ob >> 4) & 3) ^ ((row >> 1) & 3);  // inverse swizzle on source
        int kst = h >> 1;
        if ((h & 1) == 0) srcp[h][j] = A + (size_t)(m0 + row)*K + kst*32 + sl*8;
        else              srcp[h][j] = B + (size_t)(n0 + row)*K + kst*32 + sl*8;
      }
    }
  }

#define STAGE(h_, p_, kt_)                                                          \
  {                                                                                 \
    __builtin_amdgcn_global_load_lds(                                               \
      (const __attribute__((address_space(1))) void*)(srcp[h_][0] + (kt_)*64),      \
      (__attribute__((address_space(3))) void*)(ldsB + (((h_)&1)*65536 + (p_)*32768 \
          + ((h_)>>1)*16384 + wave*2048)), 16, 0, 0);                               \
    __builtin_amdgcn_global_load_lds(                                               \
      (const __attribute__((address_space(1))) void*)(srcp[h_][1] + (kt_)*64),      \
      (__attribute__((address_space(3))) void*)(ldsB + (((h_)&1)*65536 + (p_)*32768 \
          + ((h_)>>1)*16384 + wave*2048 + 1024)), 16, 0, 0);                        \
  }

  // ds_read lane offsets (swizzled slot; lane-constant since (row>>1)&3 == (ln>>1)&3)
  const int slq16 = (quad ^ ((ln >> 1) & 3)) * 16;
  const int aoffL = (wm*128 + ln)*64 + slq16;
  const int boffL = (wn*64  + ln)*64 + slq16;

  floatx4 zf = {0.f, 0.f, 0.f, 0.f};
  floatx4 acc[8][4];
#pragma unroll
  for (int i = 0; i < 8; ++i)
#pragma unroll
    for (int j = 0; j < 4; ++j) acc[i][j] = zf;

  // prologue: stage tile 0 (queue: h0,h1,h2,h3 = 8 loads); confirm h0,h1 (kst0)
  STAGE(0, 0, 0) STAGE(1, 0, 0) STAGE(2, 0, 0) STAGE(3, 0, 0)
  asm volatile("s_waitcnt vmcnt(4)");
  __builtin_amdgcn_s_barrier();

  const int NT = K >> 6;
  for (int t = 0; t < NT; ++t) {
    const int p  = t & 1;
    const int np = p ^ 1;
    const char* ab = ldsB + p*32768;            // A, kst0
    const char* bb = ldsB + 65536 + p*32768;    // B, kst0
    short8 af[4], bq[4];

    // ---- PH0: kst0, m-frags 0..3 ----
#pragma unroll
    for (int j = 0; j < 4; ++j) bq[j] = *(const short8*)(bb + boffL + j*1024);
#pragma unroll
    for (int i = 0; i < 4; ++i) af[i] = *(const short8*)(ab + aoffL + i*1024);
    if (t + 1 < NT) STAGE(0, np, t+1)
    __builtin_amdgcn_s_barrier();
    asm volatile("s_waitcnt lgkmcnt(0)");
    __builtin_amdgcn_sched_barrier(0);
    __builtin_amdgcn_s_setprio(1);
#pragma unroll
    for (int i = 0; i < 4; ++i)
#pragma unroll
      for (int j = 0; j < 4; ++j)
        acc[i][j] = __builtin_amdgcn_mfma_f32_16x16x32_bf16(af[i], bq[j], acc[i][j], 0, 0, 0);
    __builtin_amdgcn_s_setprio(0);
    __builtin_amdgcn_s_barrier();

    // ---- PH1: kst0, m-frags 4..7 (bq reused); end: confirm kst1 halves of t ----
#pragma unroll
    for (int i = 0; i < 4; ++i) af[i] = *(const short8*)(ab + aoffL + (4+i)*1024);
    if (t + 1 < NT) STAGE(1, np, t+1)
    __builtin_amdgcn_s_barrier();
    asm volatile("s_waitcnt lgkmcnt(0)");
    __builtin_amdgcn_sched_barrier(0);
    __builtin_amdgcn_s_setprio(1);
#pragma unroll
    for (int i = 0; i < 4; ++i)
#pragma unroll
      for (int j = 0; j < 4; ++j)
        acc[4+i][j] = __builtin_amdgcn_mfma_f32_16x16x32_bf16(af[i], bq[j], acc[4+i][j], 0, 0, 0);
    __builtin_amdgcn_s_setprio(0);
    if (t + 1 < NT) { asm volatile("s_waitcnt vmcnt(4)"); }   // h2,h3(t) landed
    else            { asm volatile("s_waitcnt vmcnt(0)"); }   // last tile: drain
    __builtin_amdgcn_s_barrier();

    // ---- PH2: kst1, m-frags 0..3 ----
#pragma unroll
    for (int j = 0; j < 4; ++j) bq[j] = *(const short8*)(bb + 16384 + boffL + j*1024);
#pragma unroll
    for (int i = 0; i < 4; ++i) af[i] = *(const short8*)(ab + 16384 + aoffL + i*1024);
    if (t + 1 < NT) STAGE(2, np, t+1)
    __builtin_amdgcn_s_barrier();
    asm volatile("s_waitcnt lgkmcnt(0)");
    __builtin_amdgcn_sched_barrier(0);
    __builtin_amdgcn_s_setprio(1);
#pragma unroll
    for (int i = 0; i < 4; ++i)
#pragma unroll
      for (int j = 0; j < 4; ++j)
        acc[i][j] = __builtin_amdgcn_mfma_f32_16x16x32_bf16(af[i], bq[j], acc[i][j], 0, 0, 0);
    __builtin_amdgcn_s_setprio(0);
    __builtin_amdgcn_s_barrier();

    // ---- PH3: kst1, m-frags 4..7; end: confirm kst0 halves of t+1 ----
#pragma unroll
    for (int i = 0; i < 4; ++i) af[i] = *(const short8*)(ab + 16384 + aoffL + (4+i)*1024);
    if (t + 1 < NT) STAGE(3, np, t+1)
    __builtin_amdgcn_s_barrier();
    asm volatile("s_waitcnt lgkmcnt(0)");
    __builtin_amdgcn_sched_barrier(0);
    __builtin_amdgcn_s_setprio(1);
#pragma unroll
    for (int i = 0; i < 4; ++i)
#pragma unroll
      for (int j = 0; j < 4; ++j)
        acc[4+i][j] = __builtin_amdgcn_mfma_f32_16x16x32_bf16(af[i], bq[j], acc[4+i][j], 0, 0, 0);
    __builtin_amdgcn_s_setprio(0);
    if (t + 1 < NT) { asm volatile("s_waitcnt vmcnt(4)"); }   // h0,h1(t+1) landed
    __builtin_amdgcn_s_barrier();
  }
#undef STAGE

  // ---- epilogue ----
#pragma unroll
  for (int i = 0; i < 8; ++i) {
#pragma unroll
    for (int j = 0; j < 4; ++j) {
      int row = m0 + wm*128 + i*16 + quad*4;
      int col = n0 + wn*64  + j*16 + ln;
      float bv_ = HAS_BIAS ? bias[col] : 0.f;
#pragma unroll
      for (int r = 0; r < 4; ++r) {
        float v = acc[i][j][r] + bv_;
        if (BF16_OUT) ((u16*)Cout)[(size_t)(row+r)*N + col] = f2bf(v);
        else          ((float*)Cout)[(size_t)(row+r)*N + col] = v;
      }
    }
  }
}

// ---------------- 128x256 2-phase GEMM (m201 schedule, half-M tile) ----------------
// Used ONLY for QKV projection: 32m x 24n tiles, 768 blocks = 3 exact rounds.
// Concurrency-aware 2D XCD swizzle: each round is a 32m x 8n slab; XCD grid 4x2
// of 8m x 4n rects (A 8 MB + B 8 MB live/XCD); each XCD's m-slice is ROUND-INVARIANT
// (A stays L2-warm across rounds; only the n-offset advances). Fixes R9's 705 MB fetch.
template<int BF16_OUT, int HAS_BIAS>
__global__ __launch_bounds__(512, 2) void gemm_nt_8p_h(const u16* __restrict__ A, const u16* __restrict__ B,
                                                       const float* __restrict__ bias, void* __restrict__ Cout,
                                                       int M, int N, int K)
{
  __shared__ __align__(16) u16 lds[49152];   // 96 KB: A [0,32K) {p:16K, kst:8K}, B [32K,96K) {p:32K, kst:16K}
  char* ldsB = (char*)lds;
  const int tid  = threadIdx.x;
  const int lane = tid & 63;
  const int wave = tid >> 6;        // 0..7
  const int ln   = lane & 15;
  const int quad = lane >> 4;
  const int wm   = wave >> 2;       // 0..1 (M half: 64 rows)
  const int wn   = wave & 3;        // 0..3 (N quarter: 64 cols)

  // 2D XCD rect swizzle (32x24 tiles of 128x256, 768 blocks = 3 rounds of 32m x 8n)
  const int xcd = blockIdx.x & 7;
  const int w_  = blockIdx.x >> 3;          // 0..95
  const int rnd = w_ >> 5;                  // 0..2 (n-slab sweep)
  const int wi  = w_ & 31;
  const int m0  = ((xcd >> 1) * 8 + (wi & 7)) * 128;            // m-tile 0..31 (round-invariant)
  const int n0  = (rnd * 8 + (xcd & 1) * 4 + (wi >> 3)) * 256;  // n-tile 0..23

  // staging sources: A half = 8 KB (1 glds/wave), B half = 16 KB (2 glds/wave)
  const u16* srcA[2];
  const u16* srcB[2][2];
  {
    int ob  = wave*1024 + lane*16;
    int row = ob >> 6;
    int sl  = ((ob >> 4) & 3) ^ ((row >> 1) & 3);
#pragma unroll
    for (int kst = 0; kst < 2; ++kst)
      srcA[kst] = A + (size_t)(m0 + row)*K + kst*32 + sl*8;
  }
#pragma unroll
  for (int j = 0; j < 2; ++j) {
    int ob  = wave*2048 + j*1024 + lane*16;
    int row = ob >> 6;
    int sl  = ((ob >> 4) & 3) ^ ((row >> 1) & 3);
#pragma unroll
    for (int kst = 0; kst < 2; ++kst)
      srcB[kst][j] = B + (size_t)(n0 + row)*K + kst*32 + sl*8;
  }

#define STAGEH(kst_, p_, kt_)                                                        \
  {                                                                                  \
    __builtin_amdgcn_global_load_lds(                                                \
      (const __attribute__((address_space(1))) void*)(srcA[kst_] + (kt_)*64),        \
      (__attribute__((address_space(3))) void*)(ldsB + ((p_)*16384 + (kst_)*8192     \
          + wave*1024)), 16, 0, 0);                                                  \
    __builtin_amdgcn_global_load_lds(                                                \
      (const __attribute__((address_space(1))) void*)(srcB[kst_][0] + (kt_)*64),     \
      (__attribute__((address_space(3))) void*)(ldsB + (32768 + (p_)*32768           \
          + (kst_)*16384 + wave*2048)), 16, 0, 0);                                   \
    __builtin_amdgcn_global_load_lds(                                                \
      (const __attribute__((address_space(1))) void*)(srcB[kst_][1] + (kt_)*64),     \
      (__attribute__((address_space(3))) void*)(ldsB + (32768 + (p_)*32768           \
          + (kst_)*16384 + wave*2048 + 1024)), 16, 0, 0);                            \
  }

  // ds_read lane offsets
  const int slq16 = (quad ^ ((ln >> 1) & 3)) * 16;
  const int aoffL = (wm*64 + ln)*64 + slq16;
  const int boffL = (wn*64 + ln)*64 + slq16;

  floatx4 zf = {0.f, 0.f, 0.f, 0.f};
  floatx4 acc[4][4];
#pragma unroll
  for (int i = 0; i < 4; ++i)
#pragma unroll
    for (int j = 0; j < 4; ++j) acc[i][j] = zf;

  // prologue: stage tile 0 (6 loads: kst0 = 3, kst1 = 3); confirm kst0
  STAGEH(0, 0, 0) STAGEH(1, 0, 0)
  asm volatile("s_waitcnt vmcnt(3)");
  __builtin_amdgcn_s_barrier();

  const int NT = K >> 6;
  for (int t = 0; t < NT; ++t) {
    const int p  = t & 1;
    const int np = p ^ 1;
    const char* ab = ldsB + p*16384;
    const char* bb = ldsB + 32768 + p*32768;
    short8 af[4], bq[4];

    // ---- PH0: kst0 ----
#pragma unroll
    for (int j = 0; j < 4; ++j) bq[j] = *(const short8*)(bb + boffL + j*1024);
#pragma unroll
    for (int i = 0; i < 4; ++i) af[i] = *(const short8*)(ab + aoffL + i*1024);
    if (t + 1 < NT) STAGEH(0, np, t+1)
    __builtin_amdgcn_s_barrier();
    asm volatile("s_waitcnt lgkmcnt(0)");
    __builtin_amdgcn_sched_barrier(0);
    __builtin_amdgcn_s_setprio(1);
#pragma unroll
    for (int i = 0; i < 4; ++i)
#pragma unroll
      for (int j = 0; j < 4; ++j)
        acc[i][j] = __builtin_amdgcn_mfma_f32_16x16x32_bf16(af[i], bq[j], acc[i][j], 0, 0, 0);
    __builtin_amdgcn_s_setprio(0);
    if (t + 1 < NT) { asm volatile("s_waitcnt vmcnt(3)"); }   // kst1(t) landed
    else            { asm volatile("s_waitcnt vmcnt(0)"); }   // last tile: drain
    __builtin_amdgcn_s_barrier();

    // ---- PH1: kst1; end: confirm kst0 of t+1 ----
#pragma unroll
    for (int j = 0; j < 4; ++j) bq[j] = *(const short8*)(bb + 16384 + boffL + j*1024);
#pragma unroll
    for (int i = 0; i < 4; ++i) af[i] = *(const short8*)(ab + 8192 + aoffL + i*1024);
    if (t + 1 < NT) STAGEH(1, np, t+1)
    __builtin_amdgcn_s_barrier();
    asm volatile("s_waitcnt lgkmcnt(0)");
    __builtin_amdgcn_sched_barrier(0);
    __builtin_amdgcn_s_setprio(1);
#pragma unroll
    for (int i = 0; i < 4; ++i)
#pragma unroll
      for (int j = 0; j < 4; ++j)
        acc[i][j] = __builtin_amdgcn_mfma_f32_16x16x32_bf16(af[i], bq[j], acc[i][j], 0, 0, 0);
    __builtin_amdgcn_s_setprio(0);
    if (t + 1 < NT) { asm volatile("s_waitcnt vmcnt(3)"); }   // kst0(t+1) landed
    __builtin_amdgcn_s_barrier();
  }
#undef STAGEH

  // ---- epilogue ----
#pragma unroll
  for (int i = 0; i < 4; ++i) {
#pragma unroll
    for (int j = 0; j < 4; ++j) {
      int row = m0 + wm*64 + i*16 + quad*4;
      int col = n0 + wn*64 + j*16 + ln;
      float bv_ = HAS_BIAS ? bias[col] : 0.f;
#pragma unroll
      for (int r = 0; r < 4; ++r) {
        float v = acc[i][j][r] + bv_;
        if (BF16_OUT) ((u16*)Cout)[(size_t)(row+r)*N + col] = f2bf(v);
        else          ((float*)Cout)[(size_t)(row+r)*N + col] = v;
      }
    }
  }
}

// ---------------- RoPE (strided in/out: reads fused QKV buffer) ----------------
__global__ __launch_bounds__(256) void rope_kernel(const u16* __restrict__ X, u16* __restrict__ Y,
                                                   const float* __restrict__ cosb, const float* __restrict__ sinb,
                                                   int nheads, int total, int istride, int ostride)
{
  int idx = blockIdx.x * 256 + threadIdx.x;
  if (idx >= total) return;
  int d = idx & 63;
  int t = idx >> 6;
  int hh = t % nheads;
  int row = t / nheads;
  int s = row & (SEQ_ - 1);
  size_t bi = (size_t)row * istride + hh * HD_;
  size_t bo = (size_t)row * ostride + hh * HD_;
  float x1 = bf2f(X[bi + 2*d]);
  float x2 = bf2f(X[bi + 2*d + 1]);
  float c  = cosb[s*64 + d];
  float sn = sinb[s*64 + d];
  Y[bo + d]      = f2bf(x1*c - x2*sn);
  Y[bo + 64 + d] = f2bf(x1*sn + x2*c);
}

// ---------------- Flash attention (GQA, no mask) ----------------
// 8-wave, launch_bounds(512,2); 512 blocks = 2 resident/CU, 16 waves/CU.
// SWAPPED QK^T, kappa P-layout, defer-max, async K/V staging (see R6 notes).
#define KS_TILE (64*128)

__global__ __launch_bounds__(512, 2) void attn_fwd(const u16* __restrict__ Q, const u16* __restrict__ K,
                                                   const u16* __restrict__ V, u16* __restrict__ O)
{
  __shared__ __align__(16) u16 Ks[2*KS_TILE];  // double-buffered [key][dgp swizzled], 32 KB
  __shared__ __align__(16) u16 Vt[128*72];     // [d][kappa], stride 72, 18 KB
  const int tid  = threadIdx.x;
  const int lane = tid & 63;
  const int wave = tid >> 6;      // 0..7
  const int ln   = lane & 15;
  const int quad = lane >> 4;
  // bijective XCD swizzle: 512 blocks, 8 XCDs, 64 blocks/XCD; same-XCD blocks share bh range
  const int lin = (blockIdx.x & 7) * 64 + (blockIdx.x >> 3);
  const int bh  = lin >> 3;       // 0..63
  const int b   = bh >> 5;
  const int h   = bh & 31;
  const int kvh = h >> 2;
  const int q0  = (lin & 7) * 256;

  // Q fragments: B-layout for swapped mfma (n = ln = q-row, k = kst*32 + quad*8 + j)
  short8 qf[2][4];
#pragma unroll
  for (int mt = 0; mt < 2; ++mt) {
    const u16* qbase = Q + (size_t)(b*SEQ_ + q0 + wave*32 + mt*16 + ln) * H_ + h * HD_;
#pragma unroll
    for (int kst = 0; kst < 4; ++kst)
      qf[mt][kst] = *(const short8*)(qbase + kst*32 + quad*8);
  }

  // ones B-frag: B[k][n] = (n==0) ? 1 : 0  -> lanes with ln==0 hold bf16 1.0
  short8 bones;
  {
    short v1 = (ln == 0) ? (short)0x3F80 : (short)0;
#pragma unroll
    for (int j = 0; j < 8; ++j) bones[j] = v1;
  }

  // precomputed K staging addresses: 8 waves x 2 glds x 1 KB = 16 KB/tile
  int kou[2];
  const u16* ks0[2];
#pragma unroll
  for (int i = 0; i < 2; ++i) {
    int ou = wave*2048 + i*1024;          // wave-uniform LDS byte offset
    int ob = ou + lane*16;                // this lane's dest byte
    int key = ob >> 8;                    // 256 B per key row
    int dgp = (ob >> 4) & 15;
    int dgl = dgp ^ (key & 15);
    kou[i] = ou;
    ks0[i] = K + (size_t)(b*SEQ_ + key)*KVW_ + kvh*HD_ + dgl*8;
  }
  // V staging: thread (j2, dg, g) loads keys (j2*2+jj)*16+g (jj=0,1), d-block dg
  const int g  = tid & 15;
  const int dg = (tid >> 4) & 15;
  const int j2 = tid >> 8;              // 0..1
  const u16* vs0 = V + (size_t)(b*SEQ_ + j2*32 + g)*VSTRIDE_ + kvh*HD_ + dg*8;
  const int k0v = ((g >> 1) & 1)*32 + (g >> 2)*8 + (g & 1)*4 + j2*2;  // kappa base

  floatx4 zf = {0.f, 0.f, 0.f, 0.f};
  floatx4 o[2][8];
  floatx4 ol[2];
#pragma unroll
  for (int mt = 0; mt < 2; ++mt) {
    ol[mt] = zf;
#pragma unroll
    for (int jt = 0; jt < 8; ++jt) o[mt][jt] = zf;
  }
  float mrow[2] = {-1e30f, -1e30f};   // running max for q = ln (t-domain)

  // ---- prologue: stage tile 0 ----
  int4 vreg[2];
#pragma unroll
  for (int i = 0; i < 2; ++i)
    __builtin_amdgcn_global_load_lds((const __attribute__((address_space(1))) void*)ks0[i],
        (__attribute__((address_space(3))) void*)((char*)Ks + kou[i]), 16, 0, 0);
#pragma unroll
  for (int jj = 0; jj < 2; ++jj)
    vreg[jj] = *(const int4*)(vs0 + (size_t)(jj*16)*VSTRIDE_);
  {
    union { int4 v; u16 u[8]; } w[2];
    w[0].v = vreg[0]; w[1].v = vreg[1];
#pragma unroll
    for (int dd = 0; dd < 8; ++dd) {
      ushort2 t2; t2.x = w[0].u[dd]; t2.y = w[1].u[dd];
      *(ushort2*)&Vt[(dg*8 + dd)*72 + k0v] = t2;
    }
  }
  __syncthreads();

  const int NT = SEQ_ / 64;
  for (int t = 0; t < NT; ++t) {
    // ---- issue next tile's loads early (latency hides under compute) ----
    if (t + 1 < NT) {
      size_t roff = (size_t)(t+1) * 64 * KVW_;
      char* kb = (char*)Ks + ((t+1)&1) * (KS_TILE*2);
#pragma unroll
      for (int i = 0; i < 2; ++i)
        __builtin_amdgcn_global_load_lds((const __attribute__((address_space(1))) void*)(ks0[i] + roff),
            (__attribute__((address_space(3))) void*)(kb + kou[i]), 16, 0, 0);
      size_t voff = (size_t)(t+1) * 64 * VSTRIDE_;
#pragma unroll
      for (int jj = 0; jj < 2; ++jj)
        vreg[jj] = *(const int4*)(vs0 + voff + (size_t)(jj*16)*VSTRIDE_);
    }
    const u16* Kc = Ks + (t&1)*KS_TILE;

    // ---- S^T = K Q^T (swapped): lane holds q=ln, keys nt*16+quad*4+r ----
    floatx4 s[2][4];
#pragma unroll
    for (int nt = 0; nt < 4; ++nt) { s[0][nt] = zf; s[1][nt] = zf; }
    __builtin_amdgcn_s_setprio(1);
#pragma unroll
    for (int kst = 0; kst < 4; ++kst) {
      int dgp = (kst*4 + quad) ^ ln;
#pragma unroll
      for (int nt = 0; nt < 4; ++nt) {
        short8 kf = *(const short8*)&Kc[(nt*16 + ln)*128 + dgp*8];
        s[0][nt] = __builtin_amdgcn_mfma_f32_16x16x32_bf16(kf, qf[0][kst], s[0][nt], 0, 0, 0);
        s[1][nt] = __builtin_amdgcn_mfma_f32_16x16x32_bf16(kf, qf[1][kst], s[1][nt], 0, 0, 0);
      }
    }
    __builtin_amdgcn_s_setprio(0);

    // ---- online softmax: lane-local 16-max + cross-quad reduce ----
    float rmv[2];
    bool ok = true;
#pragma unroll
    for (int mt = 0; mt < 2; ++mt) {
      float m0_ = fmaxf(fmaxf(s[mt][0][0], s[mt][0][1]), fmaxf(s[mt][0][2], s[mt][0][3]));
      float m1_ = fmaxf(fmaxf(s[mt][1][0], s[mt][1][1]), fmaxf(s[mt][1][2], s[mt][1][3]));
      float m2_ = fmaxf(fmaxf(s[mt][2][0], s[mt][2][1]), fmaxf(s[mt][2][2], s[mt][2][3]));
      float m3_ = fmaxf(fmaxf(s[mt][3][0], s[mt][3][1]), fmaxf(s[mt][3][2], s[mt][3][3]));
      float rm = fmaxf(fmaxf(m0_, m1_), fmaxf(m2_, m3_)) * TSCALE_;
      rm = fmaxf(rm, __shfl_xor(rm, 16));
      rm = fmaxf(rm, __shfl_xor(rm, 32));
      rmv[mt] = rm;
      ok = ok && (rm - mrow[mt] <= 8.0f);
    }
    // defer-max: rescale only when some row's max grew by > 8 (P bounded by 2^8)
    if (!__all(ok)) {
#pragma unroll
      for (int mt = 0; mt < 2; ++mt) {
        float mn = fmaxf(mrow[mt], rmv[mt]);
        float al = exp2f(mrow[mt] - mn);
        mrow[mt] = mn;
        float av[4];
#pragma unroll
        for (int r = 0; r < 4; ++r) av[r] = __shfl(al, (lane & 48) | (quad*4 + r));
#pragma unroll
        for (int r = 0; r < 4; ++r) {
          float a_ = av[r];
#pragma unroll
          for (int jt = 0; jt < 8; ++jt) o[mt][jt][r] *= a_;
          ol[mt][r] *= a_;
        }
      }
    }
    // ---- P = exp2(S*T - m), packed in-register directly into PV A-frags ----
    short8 pa[2][2];
#pragma unroll
    for (int mt = 0; mt < 2; ++mt) {
      float mn = mrow[mt];
      float p[4][4];
#pragma unroll
      for (int nt = 0; nt < 4; ++nt)
#pragma unroll
        for (int r = 0; r < 4; ++r)
          p[r][nt] = exp2f(fmaf(s[mt][nt][r], TSCALE_, -mn));
#pragma unroll
      for (int k2 = 0; k2 < 2; ++k2) {
        union { unsigned u[4]; short8 v; } pk;
        pk.u[0] = cvt_pk_bf16(p[2*k2][0],   p[2*k2][1]);
        pk.u[1] = cvt_pk_bf16(p[2*k2][2],   p[2*k2][3]);
        pk.u[2] = cvt_pk_bf16(p[2*k2+1][0], p[2*k2+1][1]);
        pk.u[3] = cvt_pk_bf16(p[2*k2+1][2], p[2*k2+1][3]);
        pa[mt][k2] = pk.v;
      }
    }

    // ---- O += P V (contraction over kappa; V-frags shared across m-tiles) ----
    __builtin_amdgcn_s_setprio(1);
#pragma unroll
    for (int k2 = 0; k2 < 2; ++k2) {
#pragma unroll
      for (int jt = 0; jt < 8; ++jt) {
        short8 vf = *(const short8*)&Vt[(jt*16 + ln)*72 + k2*32 + quad*8];
        o[0][jt] = __builtin_amdgcn_mfma_f32_16x16x32_bf16(pa[0][k2], vf, o[0][jt], 0, 0, 0);
        o[1][jt] = __builtin_amdgcn_mfma_f32_16x16x32_bf16(pa[1][k2], vf, o[1][jt], 0, 0, 0);
      }
      ol[0] = __builtin_amdgcn_mfma_f32_16x16x32_bf16(pa[0][k2], bones, ol[0], 0, 0, 0);
      ol[1] = __builtin_amdgcn_mfma_f32_16x16x32_bf16(pa[1][k2], bones, ol[1], 0, 0, 0);
    }
    __builtin_amdgcn_s_setprio(0);

    __syncthreads();                // all waves done reading Vt; vmcnt drained
    if (t + 1 < NT) {
      union { int4 v; u16 u[8]; } w[2];
      w[0].v = vreg[0]; w[1].v = vreg[1];
#pragma unroll
      for (int dd = 0; dd < 8; ++dd) {
        ushort2 t2; t2.x = w[0].u[dd]; t2.y = w[1].u[dd];
        *(ushort2*)&Vt[(dg*8 + dd)*72 + k0v] = t2;
      }
    }
    __syncthreads();                // next tile's Vt/Ks visible
  }

  // ---- epilogue: broadcast l from ln==0 lane of each quad, divide, store ----
#pragma unroll
  for (int mt = 0; mt < 2; ++mt) {
#pragma unroll
    for (int r = 0; r < 4; ++r) {
      float lv = __shfl(ol[mt][r], lane & 48);
      float inv = 1.f / lv;
      size_t row = (size_t)(b*SEQ_ + q0 + wave*32 + mt*16 + quad*4 + r);
      u16* dst = O + row * H_ + h * HD_ + ln;
#pragma unroll
      for (int jt = 0; jt < 8; ++jt)
        dst[jt*16] = f2bf(o[mt][jt][r] * inv);
    }
  }
}

// ---------------- host ----------------
extern "C" void kernel_launch(void* const* d_in, const int* in_sizes, int n_in,
                              void* d_out, int out_size, void* d_ws, size_t ws_size,
                              hipStream_t stream) {
  const float* hs   = (const float*)d_in[0];
  const float* cosb = (const float*)d_in[1];
  const float* sinb = (const float*)d_in[2];
  const float* Wq   = (const float*)d_in[3];
  const float* Wk   = (const float*)d_in[4];
  const float* bk   = (const float*)d_in[5];
  const float* Wv   = (const float*)d_in[6];
  const float* bv   = (const float*)d_in[7];
  const float* Wo   = (const float*)d_in[8];
  float* out = (float*)d_out;

  char* ws = (char*)d_ws;
  u16*   hs_bf   = (u16*)(ws +          0);  // 33,554,432 B (dead after QKV gemm)
  u16*   Wqkv_bf = (u16*)(ws +   33554432);  // 50,331,648  [6144][4096]
  u16*   Wo_bf   = (u16*)(ws +   83886080);  // 33,554,432
  u16*   QKV0    = (u16*)(ws +  117440512);  // 50,331,648  [4096][6144]
  u16*   Qr      = (u16*)(ws +  167772160);  // 33,554,432
  u16*   Kr      = (u16*)(ws +  201326592);  //  8,388,608
  float* biasqkv = (float*)(ws + 209715200); //     24,576
  u16*   Oa      = hs_bf;                    // alias: hs_bf dead before attn writes

  // fused convert of all 5 fp32 tensors (1 launch) + bias concat
  cvt_all<<<2048, 256, 0, stream>>>(hs, Wq, Wk, Wv, Wo, hs_bf, Wqkv_bf, Wo_bf);
  bias_concat<<<(NQKV_ + 255)/256, 256, 0, stream>>>(bk, bv, biasqkv);

  // fused Q|K|V projection: C[4096][6144], 32x24 = 768 blocks = exactly 3 full rounds
  gemm_nt_8p_h<1,1><<<dim3((ROWS_/128)*(NQKV_/256)), dim3(512), 0, stream>>>(hs_bf, Wqkv_bf, biasqkv, QKV0, ROWS_, NQKV_, H_);
  rope_kernel<<<(ROWS_*NH_*64)/256,  256, 0, stream>>>(QKV0,       Qr, cosb, sinb, NH_,  ROWS_*NH_*64,  NQKV_, H_);
  rope_kernel<<<(ROWS_*NKV_*64)/256, 256, 0, stream>>>(QKV0 + H_,  Kr, cosb, sinb, NKV_, ROWS_*NKV_*64, NQKV_, KVW_);
  // 512 blocks of 512 threads = exactly 2 blocks/CU, 16 waves/CU
  attn_fwd<<<dim3(512), dim3(512), 0, stream>>>(Qr, Kr, QKV0 + H_ + KVW_, Oa);
  // output projection: 16x16=256 blocks = exactly 1 full round
  gemm_nt_8p<0,0><<<dim3((ROWS_/256)*(H_/256)), dim3(512), 0, stream>>>(Oa, Wo_bf, nullptr, out, ROWS_, H_, H_);
}